// Round 1
// baseline (275.489 us; speedup 1.0000x reference)
//
#include <hip/hip_runtime.h>
#include <hip/hip_bf16.h>

typedef __bf16 bf16;
typedef bf16 bf16x8 __attribute__((ext_vector_type(8)));
typedef float f32x4 __attribute__((ext_vector_type(4)));

// ---------------------------------------------------------------------------
// Transpose-convert: Wt[n][k] = (bf16) W[k][n],  W is 1024x1024 f32.
// ---------------------------------------------------------------------------
__global__ __launch_bounds__(256)
void transpose_w(const float* __restrict__ W, bf16* __restrict__ Wt) {
    __shared__ float tile[32][33];
    const int bx = blockIdx.x * 32;   // col of W
    const int by = blockIdx.y * 32;   // row of W
    const int tx = threadIdx.x;       // 0..31
    const int ty = threadIdx.y;       // 0..7
    for (int i = ty; i < 32; i += 8)
        tile[i][tx] = W[(size_t)(by + i) * 1024 + bx + tx];
    __syncthreads();
    for (int i = ty; i < 32; i += 8)
        Wt[(size_t)(bx + i) * 1024 + by + tx] = (bf16)tile[tx][i];
}

// ---------------------------------------------------------------------------
// NT GEMM: C[m][n] = sum_k A[m][k] * Bt[n][k]   (both operands row-contig in k)
// 128x128 block tile, 4 waves (2x2) of 64x64, BK=64, mfma_f32_16x16x32_bf16.
// A: f32 (converted during staging) or bf16.  Bt: always bf16.
// Epilogue: optional f32 write (x scale), optional bf16 write (optionally
// transposed, for building V^T).
// CAUSAL: skip tiles with bx > by (BM==BN==128).
// KLIM: limit k-loop to (by+1)*128 (PV causal saving).
// ---------------------------------------------------------------------------
template<bool AF32, bool CAUSAL, bool KLIM, bool TWRITE>
__global__ __launch_bounds__(256)
void gemm_nt(const void* __restrict__ Ap, const void* __restrict__ Bp,
             float* __restrict__ Cf, bf16* __restrict__ Cb,
             int K, int ldA, int ldB, int ldCf, int ldCb,
             long long sA, long long sB, long long sCf, long long sCb,
             float scale)
{
    if (CAUSAL && blockIdx.x > blockIdx.y) return;
    const int bx = blockIdx.x, by = blockIdx.y, bz = blockIdx.z;
    int kEnd = K;
    if (KLIM) { int ke = (by + 1) * 128; if (ke < kEnd) kEnd = ke; }

    __shared__ bf16 lA[128][72];   // +8 pad: keeps 16B align (144B rows), spreads banks
    __shared__ bf16 lB[128][72];

    const int t    = threadIdx.x;
    const int lane = t & 63;
    const int wid  = t >> 6;
    const int wr   = (wid >> 1) * 64;
    const int wc   = (wid & 1) * 64;
    const int rl   = lane & 15;
    const int kb8  = (lane >> 4) * 8;

    const int r0 = t >> 3;        // 0..31  (staging row)
    const int c0 = (t & 7) * 8;   // 0..56  (staging col, 8 elems)

    f32x4 acc[4][4] = {};

    for (int kt = 0; kt < kEnd; kt += 64) {
#pragma unroll
        for (int it = 0; it < 4; ++it) {
            const int r = it * 32 + r0;
            if (AF32) {
                const float* s = (const float*)Ap + sA * bz
                               + (long long)(by * 128 + r) * ldA + kt + c0;
                float4 f0 = *(const float4*)s;
                float4 f1 = *(const float4*)(s + 4);
                bf16x8 v;
                v[0] = (bf16)f0.x; v[1] = (bf16)f0.y; v[2] = (bf16)f0.z; v[3] = (bf16)f0.w;
                v[4] = (bf16)f1.x; v[5] = (bf16)f1.y; v[6] = (bf16)f1.z; v[7] = (bf16)f1.w;
                *(bf16x8*)&lA[r][c0] = v;
            } else {
                const bf16* s = (const bf16*)Ap + sA * bz
                              + (long long)(by * 128 + r) * ldA + kt + c0;
                *(bf16x8*)&lA[r][c0] = *(const bf16x8*)s;
            }
            {
                const bf16* s = (const bf16*)Bp + sB * bz
                              + (long long)(bx * 128 + r) * ldB + kt + c0;
                *(bf16x8*)&lB[r][c0] = *(const bf16x8*)s;
            }
        }
        __syncthreads();
#pragma unroll
        for (int ks = 0; ks < 2; ++ks) {
            const int ko = ks * 32 + kb8;
            bf16x8 af[4], bf_[4];
#pragma unroll
            for (int m = 0; m < 4; ++m) af[m]  = *(bf16x8*)&lA[wr + m * 16 + rl][ko];
#pragma unroll
            for (int n = 0; n < 4; ++n) bf_[n] = *(bf16x8*)&lB[wc + n * 16 + rl][ko];
#pragma unroll
            for (int m = 0; m < 4; ++m)
#pragma unroll
                for (int n = 0; n < 4; ++n)
                    acc[m][n] = __builtin_amdgcn_mfma_f32_16x16x32_bf16(
                                    af[m], bf_[n], acc[m][n], 0, 0, 0);
        }
        __syncthreads();
    }

    // Epilogue.  C/D frag layout (m89): col = lane&15, row = (lane>>4)*4 + j.
    const int rg4 = (lane >> 4) * 4;
#pragma unroll
    for (int m = 0; m < 4; ++m) {
#pragma unroll
        for (int n = 0; n < 4; ++n) {
            const int row0 = by * 128 + wr + m * 16 + rg4;
            const int col  = bx * 128 + wc + n * 16 + rl;
#pragma unroll
            for (int j = 0; j < 4; ++j) {
                const float v = acc[m][n][j] * scale;
                const int row = row0 + j;
                if (Cf) Cf[sCf * bz + (long long)row * ldCf + col] = v;
                if (Cb) {
                    if (TWRITE) Cb[sCb * bz + (long long)col * ldCb + row] = (bf16)v;
                    else        Cb[sCb * bz + (long long)row * ldCb + col] = (bf16)v;
                }
            }
        }
    }
}

// ---------------------------------------------------------------------------
// Causal row softmax, in place: reads f32 scores row (already scaled), writes
// bf16 P over the same bytes (row stride stays 2048 f32 = 4096 bf16).
// Zero-fills (q, tile_end) so PV can read whole 128-tiles.
// ---------------------------------------------------------------------------
__global__ __launch_bounds__(256)
void softmax_causal(float* __restrict__ scores)
{
    __shared__ float buf[2048];
    __shared__ float red[4];
    const int row = blockIdx.x;           // 0..8191  (b*2048 + q)
    const int q   = row & 2047;
    float* srow = scores + (size_t)row * 2048;
    bf16*  prow = (bf16*)srow;            // in-place
    const int L = q + 1;
    const int t = threadIdx.x;

    float m = -INFINITY;
    for (int k = t; k < L; k += 256) {
        float v = srow[k];
        buf[k] = v;
        m = fmaxf(m, v);
    }
#pragma unroll
    for (int o = 32; o; o >>= 1) m = fmaxf(m, __shfl_xor(m, o));
    if ((t & 63) == 0) red[t >> 6] = m;
    __syncthreads();
    m = fmaxf(fmaxf(red[0], red[1]), fmaxf(red[2], red[3]));

    float s = 0.f;
    for (int k = t; k < L; k += 256) s += __expf(buf[k] - m);
#pragma unroll
    for (int o = 32; o; o >>= 1) s += __shfl_xor(s, o);
    __syncthreads();
    if ((t & 63) == 0) red[t >> 6] = s;
    __syncthreads();
    s = red[0] + red[1] + red[2] + red[3];
    const float inv = 1.f / s;

    for (int k = t; k < L; k += 256) prow[k] = (bf16)(__expf(buf[k] - m) * inv);
    const int tileEnd = ((q >> 7) + 1) << 7;
    for (int k = L + t; k < tileEnd; k += 256) prow[k] = (bf16)0.f;
}

// ---------------------------------------------------------------------------
// Launch
// ---------------------------------------------------------------------------
extern "C" void kernel_launch(void* const* d_in, const int* in_sizes, int n_in,
                              void* d_out, int out_size, void* d_ws, size_t ws_size,
                              hipStream_t stream)
{
    const float* Xk = (const float*)d_in[0];
    const float* Xv = (const float*)d_in[1];
    const float* Xq = (const float*)d_in[2];
    const float* WK = (const float*)d_in[3];
    const float* WV = (const float*)d_in[4];
    const float* WQ = (const float*)d_in[5];

    float* outQ = (float*)d_out;                       // [4,2048,1024] f32
    float* outA = outQ + (size_t)8192 * 1024;          // [4,2048,1024] f32

    char* ws = (char*)d_ws;
    bf16*  Qb     = (bf16*)(ws);                       // [8192][1024] bf16, 16MB
    bf16*  Kb     = (bf16*)(ws + (16ull << 20));       // [8192][1024] bf16, 16MB
    bf16*  Vt     = (bf16*)(ws + (32ull << 20));       // [1024][8192] bf16, 16MB
    float* scores = (float*)(ws + (48ull << 20));      // [4][2048][2048] f32, 64MB
    // Wt aliases the scores region (used only before QK^T writes scores).
    bf16*  WtQ    = (bf16*)(ws + (48ull << 20));
    bf16*  WtK    = WtQ + (size_t)1024 * 1024;
    bf16*  WtV    = WtK + (size_t)1024 * 1024;

    const float scale = 0.022097086912079608f;         // 1/sqrt(2048)

    dim3 tb(32, 8);
    transpose_w<<<dim3(32, 32), tb, 0, stream>>>(WQ, WtQ);
    transpose_w<<<dim3(32, 32), tb, 0, stream>>>(WK, WtK);
    transpose_w<<<dim3(32, 32), tb, 0, stream>>>(WV, WtV);

    // Projections: M=8192, N=1024, K=1024.  A f32, Bt = Wt bf16.
    gemm_nt<true, false, false, false><<<dim3(8, 64, 1), 256, 0, stream>>>(
        Xq, WtQ, outQ, Qb, 1024, 1024, 1024, 1024, 1024, 0, 0, 0, 0, 1.f);
    gemm_nt<true, false, false, false><<<dim3(8, 64, 1), 256, 0, stream>>>(
        Xk, WtK, nullptr, Kb, 1024, 1024, 1024, 0, 1024, 0, 0, 0, 0, 1.f);
    gemm_nt<true, false, false, true><<<dim3(8, 64, 1), 256, 0, stream>>>(
        Xv, WtV, nullptr, Vt, 1024, 1024, 1024, 0, 8192, 0, 0, 0, 0, 1.f);

    // QK^T: per batch M=N=2048, K=1024, causal tile skip; scale in epilogue.
    gemm_nt<false, true, false, false><<<dim3(16, 16, 4), 256, 0, stream>>>(
        Qb, Kb, scores, nullptr, 1024, 1024, 1024, 2048, 0,
        2048ll * 1024, 2048ll * 1024, 2048ll * 2048, 0, scale);

    // Softmax (causal, in place f32 -> bf16 P with row stride 4096 bf16).
    softmax_causal<<<dim3(8192), 256, 0, stream>>>(scores);

    // PV: per batch M=2048, N=1024, K=2048 with k-limit (by+1)*128.
    gemm_nt<false, false, true, false><<<dim3(8, 16, 4), 256, 0, stream>>>(
        (const bf16*)scores, Vt, outA, nullptr, 2048, 4096, 8192, 1024, 0,
        2048ll * 4096, 2048, 2048ll * 1024, 0, 1.f);
}

// Round 2
// 258.153 us; speedup vs baseline: 1.0672x; 1.0672x over previous
//
#include <hip/hip_runtime.h>
#include <hip/hip_bf16.h>

typedef __bf16 bf16;
typedef bf16 bf16x8 __attribute__((ext_vector_type(8)));
typedef bf16 bf16x4 __attribute__((ext_vector_type(4)));
typedef float f32x4 __attribute__((ext_vector_type(4)));

// Async 16B global -> LDS (wave-uniform LDS base + lane*16).
__device__ __forceinline__ void gload_lds16(const void* g, void* l) {
    __builtin_amdgcn_global_load_lds(
        (const __attribute__((address_space(1))) void*)g,
        (__attribute__((address_space(3))) void*)l, 16, 0, 0);
}

// ---------------------------------------------------------------------------
// Fused f32 -> bf16 convert for the three X inputs (vectorized 32B->16B/thread)
// ---------------------------------------------------------------------------
__global__ __launch_bounds__(256)
void convert_x(const float* __restrict__ X0, const float* __restrict__ X1,
               const float* __restrict__ X2,
               bf16* __restrict__ Y0, bf16* __restrict__ Y1, bf16* __restrict__ Y2)
{
    const int which = blockIdx.x >> 12;                 // 4096 blocks per tensor
    const long long base = (((long long)(blockIdx.x & 4095)) * 256 + threadIdx.x) * 8;
    const float* X = which == 0 ? X0 : which == 1 ? X1 : X2;
    bf16*       Y = which == 0 ? Y0 : which == 1 ? Y1 : Y2;
    float4 a = *(const float4*)(X + base);
    float4 b = *(const float4*)(X + base + 4);
    bf16x8 v;
    v[0] = (bf16)a.x; v[1] = (bf16)a.y; v[2] = (bf16)a.z; v[3] = (bf16)a.w;
    v[4] = (bf16)b.x; v[5] = (bf16)b.y; v[6] = (bf16)b.z; v[7] = (bf16)b.w;
    *(bf16x8*)(Y + base) = v;
}

// ---------------------------------------------------------------------------
// Transpose-convert: Wt[n][k] = (bf16) W[k][n],  W is 1024x1024 f32.
// ---------------------------------------------------------------------------
__global__ __launch_bounds__(256)
void transpose_w(const float* __restrict__ W, bf16* __restrict__ Wt) {
    __shared__ float tile[32][33];
    const int bx = blockIdx.x * 32;
    const int by = blockIdx.y * 32;
    const int tx = threadIdx.x;
    const int ty = threadIdx.y;
    for (int i = ty; i < 32; i += 8)
        tile[i][tx] = W[(size_t)(by + i) * 1024 + bx + tx];
    __syncthreads();
    for (int i = ty; i < 32; i += 8)
        Wt[(size_t)(bx + i) * 1024 + by + tx] = (bf16)tile[tx][i];
}

// ---------------------------------------------------------------------------
// NT GEMM, m97 structure: 128x128 tile, BK=64, 4 waves (2x2) of 64x64,
// linear [128][64] LDS, global_load_lds width-16 staging, 2-barrier K-loop,
// mfma_f32_16x16x32_bf16.
// CAUSAL: skip tiles with bx > by.  KLIM: k-loop capped at (by+1)*128.
// TWRITE: bf16 output written transposed (builds V^T).
// ---------------------------------------------------------------------------
template<bool CAUSAL, bool KLIM, bool TWRITE>
__global__ __launch_bounds__(256)
void gemm_nt(const bf16* __restrict__ Ap, const bf16* __restrict__ Bp,
             float* __restrict__ Cf, bf16* __restrict__ Cb,
             int K, int ldA, int ldB, int ldCf, int ldCb,
             long long sA, long long sB, long long sCf, long long sCb,
             float scale)
{
    if (CAUSAL && blockIdx.x > blockIdx.y) return;
    const int bx = blockIdx.x, by = blockIdx.y, bz = blockIdx.z;
    int kEnd = K;
    if (KLIM) { int ke = (by + 1) * 128; if (ke < kEnd) kEnd = ke; }

    __shared__ bf16 lA[128][64];   // 16KB, linear (global_load_lds dest)
    __shared__ bf16 lB[128][64];   // 16KB

    const int t    = threadIdx.x;
    const int lane = t & 63;
    const int wid  = t >> 6;
    const int wr   = (wid >> 1) * 64;
    const int wc   = (wid & 1) * 64;
    const int rl   = lane & 15;
    const int kb8  = (lane >> 4) * 8;

    const bf16* Ab = Ap + sA * bz;
    const bf16* Bb = Bp + sB * bz;

    f32x4 acc[4][4] = {};

    for (int kt = 0; kt < kEnd; kt += 64) {
#pragma unroll
        for (int i = 0; i < 4; ++i) {
            const int chunk = i * 256 + t;          // 16B chunk index in tile
            const int r  = chunk >> 3;              // tile row
            const int c8 = (chunk & 7) * 8;         // tile col (bf16 elems)
            const int ldsOff = (i * 256 + (t & ~63)) * 16;   // wave-uniform
            gload_lds16(Ab + (long long)(by * 128 + r) * ldA + kt + c8,
                        (char*)&lA[0][0] + ldsOff);
            gload_lds16(Bb + (long long)(bx * 128 + r) * ldB + kt + c8,
                        (char*)&lB[0][0] + ldsOff);
        }
        __syncthreads();
#pragma unroll
        for (int ks = 0; ks < 2; ++ks) {
            const int ko = ks * 32 + kb8;
            bf16x8 af[4], bf_[4];
#pragma unroll
            for (int m = 0; m < 4; ++m) af[m]  = *(bf16x8*)&lA[wr + m * 16 + rl][ko];
#pragma unroll
            for (int n = 0; n < 4; ++n) bf_[n] = *(bf16x8*)&lB[wc + n * 16 + rl][ko];
#pragma unroll
            for (int m = 0; m < 4; ++m)
#pragma unroll
                for (int n = 0; n < 4; ++n)
                    acc[m][n] = __builtin_amdgcn_mfma_f32_16x16x32_bf16(
                                    af[m], bf_[n], acc[m][n], 0, 0, 0);
        }
        __syncthreads();
    }

    // Epilogue. C/D frag layout (m89): col = lane&15, row = (lane>>4)*4 + j.
    const int rg4 = (lane >> 4) * 4;
#pragma unroll
    for (int m = 0; m < 4; ++m) {
#pragma unroll
        for (int n = 0; n < 4; ++n) {
            const int row0 = by * 128 + wr + m * 16 + rg4;
            const int col  = bx * 128 + wc + n * 16 + rl;
#pragma unroll
            for (int j = 0; j < 4; ++j) {
                const float v = acc[m][n][j] * scale;
                const int row = row0 + j;
                if (Cf) Cf[sCf * bz + (long long)row * ldCf + col] = v;
                if (Cb) {
                    if (TWRITE) Cb[sCb * bz + (long long)col * ldCb + row] = (bf16)v;
                    else        Cb[sCb * bz + (long long)row * ldCb + col] = (bf16)v;
                }
            }
        }
    }
}

// ---------------------------------------------------------------------------
// Causal row softmax, vectorized, in place: f32 scores row -> bf16 P over the
// same bytes (row stride stays 2048 f32 = 4096 bf16). Masked entries get
// -inf -> exp() = 0, which also provides the zero-fill up to the tile end.
// ---------------------------------------------------------------------------
__global__ __launch_bounds__(256)
void softmax_causal(float* __restrict__ scores)
{
    __shared__ float buf[2048];
    __shared__ float red[8];
    const int row = blockIdx.x;           // b*2048 + q
    const int q   = row & 2047;
    float* srow = scores + (size_t)row * 2048;
    bf16*  prow = (bf16*)srow;
    const int L = q + 1;
    const int tileEnd = ((q >> 7) + 1) << 7;   // multiple of 128, >= L
    const int t = threadIdx.x;
    const int lane = t & 63, wv = t >> 6;

    float m = -INFINITY;
    for (int k = t * 4; k < tileEnd; k += 1024) {
        float4 v = *(const float4*)(srow + k);
        float4 w;
        w.x = (k + 0 < L) ? v.x : -INFINITY;
        w.y = (k + 1 < L) ? v.y : -INFINITY;
        w.z = (k + 2 < L) ? v.z : -INFINITY;
        w.w = (k + 3 < L) ? v.w : -INFINITY;
        *(float4*)(buf + k) = w;
        m = fmaxf(fmaxf(fmaxf(m, w.x), w.y), fmaxf(w.z, w.w));
    }
#pragma unroll
    for (int o = 32; o; o >>= 1) m = fmaxf(m, __shfl_xor(m, o));
    if (lane == 0) red[wv] = m;
    __syncthreads();
    m = fmaxf(fmaxf(red[0], red[1]), fmaxf(red[2], red[3]));

    float s = 0.f;
    for (int k = t * 4; k < tileEnd; k += 1024) {
        float4 v = *(float4*)(buf + k);
        float4 e;
        e.x = __expf(v.x - m); e.y = __expf(v.y - m);
        e.z = __expf(v.z - m); e.w = __expf(v.w - m);
        s += (e.x + e.y) + (e.z + e.w);
        *(float4*)(buf + k) = e;
    }
#pragma unroll
    for (int o = 32; o; o >>= 1) s += __shfl_xor(s, o);
    if (lane == 0) red[4 + wv] = s;
    __syncthreads();
    s = (red[4] + red[5]) + (red[6] + red[7]);
    const float inv = 1.f / s;

    for (int k = t * 4; k < tileEnd; k += 1024) {
        float4 v = *(float4*)(buf + k);
        bf16x4 o;
        o[0] = (bf16)(v.x * inv); o[1] = (bf16)(v.y * inv);
        o[2] = (bf16)(v.z * inv); o[3] = (bf16)(v.w * inv);
        *(bf16x4*)(prow + k) = o;
    }
}

// ---------------------------------------------------------------------------
// Launch
// ---------------------------------------------------------------------------
extern "C" void kernel_launch(void* const* d_in, const int* in_sizes, int n_in,
                              void* d_out, int out_size, void* d_ws, size_t ws_size,
                              hipStream_t stream)
{
    const float* Xk = (const float*)d_in[0];
    const float* Xv = (const float*)d_in[1];
    const float* Xq = (const float*)d_in[2];
    const float* WK = (const float*)d_in[3];
    const float* WV = (const float*)d_in[4];
    const float* WQ = (const float*)d_in[5];

    float* outQ = (float*)d_out;                       // [4,2048,1024] f32
    float* outA = outQ + (size_t)8192 * 1024;          // [4,2048,1024] f32

    char* ws = (char*)d_ws;
    bf16*  Qb     = (bf16*)(ws);                       // 16MB
    bf16*  Kb     = (bf16*)(ws + (16ull << 20));       // 16MB
    bf16*  Vt     = (bf16*)(ws + (32ull << 20));       // 16MB  [1024][8192]
    float* scores = (float*)(ws + (48ull << 20));      // 64MB  [4][2048][2048]
    // The following alias the scores region (dead once QK^T writes scores):
    bf16*  Xqb    = (bf16*)(ws + (48ull << 20));                 // 16MB
    bf16*  Xkb    = Xqb + (size_t)8 * 1024 * 1024;               // 16MB
    bf16*  Xvb    = Xkb + (size_t)8 * 1024 * 1024;               // 16MB
    bf16*  WtQ    = Xvb + (size_t)8 * 1024 * 1024;               // 2MB
    bf16*  WtK    = WtQ + (size_t)1024 * 1024;
    bf16*  WtV    = WtK + (size_t)1024 * 1024;

    const float scale = 0.022097086912079608f;         // 1/sqrt(2048)

    convert_x<<<dim3(12288), 256, 0, stream>>>(Xq, Xk, Xv, Xqb, Xkb, Xvb);

    dim3 tb(32, 8);
    transpose_w<<<dim3(32, 32), tb, 0, stream>>>(WQ, WtQ);
    transpose_w<<<dim3(32, 32), tb, 0, stream>>>(WK, WtK);
    transpose_w<<<dim3(32, 32), tb, 0, stream>>>(WV, WtV);

    // Projections: M=8192, N=1024, K=1024 (all bf16 now).
    gemm_nt<false, false, false><<<dim3(8, 64, 1), 256, 0, stream>>>(
        Xqb, WtQ, outQ, Qb, 1024, 1024, 1024, 1024, 1024, 0, 0, 0, 0, 1.f);
    gemm_nt<false, false, false><<<dim3(8, 64, 1), 256, 0, stream>>>(
        Xkb, WtK, nullptr, Kb, 1024, 1024, 1024, 0, 1024, 0, 0, 0, 0, 1.f);
    gemm_nt<false, false, true><<<dim3(8, 64, 1), 256, 0, stream>>>(
        Xvb, WtV, nullptr, Vt, 1024, 1024, 1024, 0, 8192, 0, 0, 0, 0, 1.f);

    // QK^T: per batch M=N=2048, K=1024, causal tile skip; scale in epilogue.
    gemm_nt<true, false, false><<<dim3(16, 16, 4), 256, 0, stream>>>(
        Qb, Kb, scores, nullptr, 1024, 1024, 1024, 2048, 0,
        2048ll * 1024, 2048ll * 1024, 2048ll * 2048, 0, scale);

    // Softmax (causal, in place f32 -> bf16 P with row stride 4096 bf16).
    softmax_causal<<<dim3(8192), 256, 0, stream>>>(scores);

    // PV: per batch M=2048, N=1024, K=2048 with k-limit (by+1)*128.
    gemm_nt<false, true, false><<<dim3(8, 16, 4), 256, 0, stream>>>(
        (const bf16*)scores, Vt, outA, nullptr, 2048, 4096, 8192, 1024, 0,
        2048ll * 4096, 2048, 2048ll * 1024, 0, 1.f);
}